// Round 1
// baseline (253.338 us; speedup 1.0000x reference)
//
#include <hip/hip_runtime.h>

// Problem constants (x: (512, 9, 84, 84) f32)
#define N_ELEM   7056        // 84*84
#define DIM      84
#define M_STEPS  14111       // 2*N_ELEM - 1
#define N_ROWS   4608        // 512*9
#define NCHUNK   384
#define KSTEPS   37          // 384*37 = 14208 >= 14111 (tail chunks empty -> identity)
#define WINW     208         // window: (K-1)+2*84+1 = 205, padded to 208 (416 B = 26 uint4)
#define TPB      256
#define NJV      1764        // N_ELEM / 4

#define TRACE_BLOCKS 28      // 28 * 252 = 7056
#define GROUPS   16          // chunk groups for parallel partial maps
#define CPG      (NCHUNK / GROUPS)   // 24 chunks per group
#define ROWS_PB  4           // rows per gather block

// ---- JAX threefry2x32 block cipher (20 rounds), bit-exact port ----
__device__ __forceinline__ void threefry2x32(unsigned k0, unsigned k1,
                                             unsigned x0, unsigned x1,
                                             unsigned &o0, unsigned &o1) {
  const unsigned ks0 = k0, ks1 = k1, ks2 = k0 ^ k1 ^ 0x1BD11BDAu;
  x0 += ks0; x1 += ks1;
#define ROTL(x, r) (((x) << (r)) | ((x) >> (32 - (r))))
#define RND(r) { x0 += x1; x1 = ROTL(x1, r); x1 ^= x0; }
  RND(13) RND(15) RND(26) RND(6)
  x0 += ks1; x1 += ks2 + 1u;
  RND(17) RND(29) RND(16) RND(24)
  x0 += ks2; x1 += ks0 + 2u;
  RND(13) RND(15) RND(26) RND(6)
  x0 += ks0; x1 += ks1 + 3u;
  RND(17) RND(29) RND(16) RND(24)
  x0 += ks1; x1 += ks2 + 4u;
  RND(13) RND(15) RND(26) RND(6)
  x0 += ks2; x1 += ks0 + 5u;
  o0 = x0; o1 = x1;
#undef RND
#undef ROTL
}

// jax.random.choice(key,5,p=[.55,.1125,.1125,.1125,.1125]) — searchsorted on f32
// cumsum (sequential f32 cumsum verified exact-arithmetic: q4 == 1.0f exactly).
__device__ __forceinline__ int r_from_bits(unsigned bits) {
  const float p8 = 0.1125f;
  const float q0 = 0.55f;
  const float q1 = q0 + p8;
  const float q2 = q1 + p8;
  const float q3 = q2 + p8;
  const float q4 = q3 + p8;
  float u  = __uint_as_float((bits >> 9) | 0x3F800000u) - 1.0f; // [0,1)
  float rv = q4 * (1.0f - u);
  return (int)(q0 < rv) + (int)(q1 < rv) + (int)(q2 < rv) + (int)(q3 < rv);
}

// Window bounds for chunk c: steps t in [t0,t1); touched positions are within
// [imin-DIM, imax+DIM] clamped to [0, N_ELEM-1], where i(t) = |t - (N_ELEM-1)|.
__device__ __forceinline__ void chunk_bounds(int c, int &t0, int &t1, int &lo, int &hi) {
  t0 = c * KSTEPS; if (t0 > M_STEPS) t0 = M_STEPS;
  t1 = t0 + KSTEPS; if (t1 > M_STEPS) t1 = M_STEPS;
  int a0 = t0 - (N_ELEM - 1);       if (a0 < 0) a0 = -a0;
  int a1 = (t1 - 1) - (N_ELEM - 1); if (a1 < 0) a1 = -a1;
  int imax = a0 > a1 ? a0 : a1;
  int imin;
  if (t0 <= N_ELEM - 1 && t1 - 1 >= N_ELEM - 1) imin = 0;
  else imin = a0 < a1 ? a0 : a1;
  lo = imin - DIM; if (lo < 0) lo = 0;
  hi = imax + DIM; if (hi > N_ELEM - 1) hi = N_ELEM - 1;
}

// Kernel 1: one block per chunk (chunks independent, each starts from identity).
// Parallel threefry for the chunk's draws, then lane 0 runs the <=37 sequential
// swaps in a private LDS window; window written to global winG (26 uint4).
__global__ __launch_bounds__(TPB) void chunk_kernel(unsigned* __restrict__ winG) {
  __shared__ __align__(16) unsigned short w[WINW];
  __shared__ unsigned char rs[KSTEPS + 3];

  const int c = blockIdx.x, tid = threadIdx.x;
  int t0, t1, lo, hi; chunk_bounds(c, t0, t1, lo, hi);
  const int nt = t1 - t0;

  if (tid < WINW) w[tid] = (unsigned short)(lo + tid);   // pad entries unused
  if (tid < nt) {
    unsigned y0, y1;
    threefry2x32(0u, 42u, 0u, (unsigned)(t0 + tid), y0, y1);
    rs[tid] = (unsigned char)r_from_bits(y0 ^ y1);
  }
  __syncthreads();

  if (tid == 0) {
    for (int k = 0; k < nt; ++k) {
      int t = t0 + k;
      int i = t - (N_ELEM - 1); if (i < 0) i = -i;
      int r = rs[k];
      int off = (r == 1) ? 1 : (r == 2) ? -1 : (r == 3) ? DIM : (r == 4) ? -DIM : 0;
      int idx = i + off;
      bool doit = (r != 0) && (idx > 0) && (idx < N_ELEM);
      int je = doit ? idx : i;              // branchless self-swap when !doit
      unsigned short a = w[i  - lo];
      unsigned short b = w[je - lo];
      w[i  - lo] = b;
      w[je - lo] = a;
    }
  }
  __syncthreads();

  const uint4* w4 = (const uint4*)w;
  if (tid < WINW * 2 / 16) ((uint4*)winG)[c * (WINW * 2 / 16) + tid] = w4[tid];
}

// Kernel 2a: group-parallel partial maps. Group g covers chunks [g*CPG, g*CPG+CPG).
// Each of GROUPS*28 blocks stages its group's 24 windows (10 KB LDS) and traces
// 252 indices through the group's chunks (c descending => chunk order 383..0
// is preserved across compose). Output P_g[y] as ushort.
__global__ __launch_bounds__(TPB) void partial_trace_kernel(const unsigned* __restrict__ winG,
                                                            unsigned short* __restrict__ Pg) {
  __shared__ __align__(16) unsigned short w[CPG * WINW];  // 24*208*2 = 9984 B
  const int tid = threadIdx.x;
  const int g  = blockIdx.x / TRACE_BLOCKS;
  const int sb = blockIdx.x % TRACE_BLOCKS;
  const int U4_PER_WIN = WINW * 2 / 16;                   // 26

  uint4* w4 = (uint4*)w;
  const uint4* g4 = (const uint4*)winG + (size_t)(g * CPG) * U4_PER_WIN;
  for (int k = tid; k < CPG * U4_PER_WIN; k += TPB) w4[k] = g4[k];
  __syncthreads();

  if (tid < 252) {
    int y = sb * 252 + tid;
    for (int c = CPG - 1; c >= 0; --c) {
      int t0, t1, lo, hi; chunk_bounds(g * CPG + c, t0, t1, lo, hi);
      unsigned e = (unsigned)(y - lo);
      if (e <= (unsigned)(hi - lo)) y = (int)w[c * WINW + e];
    }
    Pg[g * N_ELEM + sb * 252 + tid] = (unsigned short)y;
  }
}

// Kernel 2b: compose the 16 partial maps: perm[j] = P_0[P_1[...P_15[j]]].
// (P_15 applied first = chunks 383..360, matching the original c=383..0 walk.)
// Tables total 226 KB -> L2/L3 resident; 16 dependent loads, trivial time.
__global__ __launch_bounds__(TPB) void compose_kernel(const unsigned short* __restrict__ Pg,
                                                      int* __restrict__ permG) {
  const int tid = threadIdx.x;
  if (tid >= 252) return;
  const int j = blockIdx.x * 252 + tid;
  int y = j;
#pragma unroll
  for (int g = GROUPS - 1; g >= 0; --g) y = (int)Pg[g * N_ELEM + y];
  permG[j] = y;
}

// Kernel 3: per-row LDS-staged gather, ROWS_PB rows per block with the perm
// held in registers (7 int4 per thread, loaded once). Coalesced float4 row
// load -> LDS -> permuted read -> coalesced float4 store.
__global__ __launch_bounds__(TPB) void gather_kernel(const float* __restrict__ x,
                                                     const int* __restrict__ perm,
                                                     float* __restrict__ out) {
  __shared__ __align__(16) float row[N_ELEM];             // 28224 B -> 5 blocks/CU
  const int tid = threadIdx.x;
  const int r0 = blockIdx.x * ROWS_PB;

  int4 p[7];
  const int4* p4 = (const int4*)perm;
#pragma unroll
  for (int k = 0; k < 7; ++k) {
    int v = tid + k * TPB;
    if (v < NJV) p[k] = p4[v];
  }

  for (int rr = 0; rr < ROWS_PB; ++rr) {
    const int r = r0 + rr;
    const float4* xr4 = (const float4*)(x + (size_t)r * N_ELEM);
    float4* row4 = (float4*)row;
#pragma unroll
    for (int k = 0; k < 7; ++k) {
      int v = tid + k * TPB;
      if (v < NJV) row4[v] = xr4[v];
    }
    __syncthreads();

    float4* or4 = (float4*)(out + (size_t)r * N_ELEM);
#pragma unroll
    for (int k = 0; k < 7; ++k) {
      int v = tid + k * TPB;
      if (v < NJV) {
        int4 pp = p[k];
        float4 o;
        o.x = row[pp.x]; o.y = row[pp.y]; o.z = row[pp.z]; o.w = row[pp.w];
        or4[v] = o;
      }
    }
    __syncthreads();   // before next row's load overwrites LDS
  }
}

extern "C" void kernel_launch(void* const* d_in, const int* in_sizes, int n_in,
                              void* d_out, int out_size, void* d_ws, size_t ws_size,
                              hipStream_t stream) {
  const float* x = (const float*)d_in[0];
  float* out = (float*)d_out;

  // ws layout: winG 159744 B | Pg 225792 B | perm 28224 B  (total ~414 KB)
  unsigned* winG = (unsigned*)d_ws;
  unsigned short* Pg = (unsigned short*)((char*)d_ws + (size_t)NCHUNK * WINW * 2);
  int* perm = (int*)((char*)d_ws + (size_t)NCHUNK * WINW * 2
                                 + (size_t)GROUPS * N_ELEM * 2);

  chunk_kernel<<<NCHUNK, TPB, 0, stream>>>(winG);
  partial_trace_kernel<<<GROUPS * TRACE_BLOCKS, TPB, 0, stream>>>(winG, Pg);
  compose_kernel<<<TRACE_BLOCKS, TPB, 0, stream>>>(Pg, perm);
  gather_kernel<<<N_ROWS / ROWS_PB, TPB, 0, stream>>>(x, perm, out);
}